// Round 14
// baseline (74.389 us; speedup 1.0000x reference)
//
#include <hip/hip_runtime.h>
#include <cmath>

typedef _Float16 half8 __attribute__((ext_vector_type(8)));
typedef _Float16 h2t   __attribute__((ext_vector_type(2)));
typedef float f32x4  __attribute__((ext_vector_type(4)));
typedef float f32x16 __attribute__((ext_vector_type(16)));

namespace {
constexpr int BB   = 64;
constexpr int TT   = 1002;
constexpr int DD   = 8;
constexpr int HH   = 64;
constexpr int LAGS = 2;
constexpr int NW   = TT - LAGS;      // 1000
constexpr int FIN  = LAGS * DD + 1;  // 17
constexpr int NTOT = BB * NW;        // 64000
constexpr int GXB  = 8;              // x-blocks; 4 waves/block; 32 windows/wave
constexpr int NSTR = 32;             // strips per (b,d)

constexpr int RES_OFF = 0;
constexpr int LOG_OFF = NTOT * DD;
constexpr int HJ_OFF  = LOG_OFF + BB;

// A-fragment pack for 32x32x16 MFMA (f16 units), layout as round 13 (verified):
// [mt][kc][lane 64][8]: m = 32*mt + (lane&31), k = kc*16 + (lane>>5)*8 + j.
constexpr int SZ_A0F = 2 * 2 * 64 * 8;   // M64 K32 (pad f>=17 -> 0)
constexpr int SZ_AH  = 2 * 4 * 64 * 8;   // M64 K64
constexpr int SZ_A0T = 1 * 4 * 64 * 8;   // M32 K64 (pad m>=17 -> 0)
constexpr int OA0F = 0;
constexpr int OA1F = OA0F + DD * SZ_A0F;
constexpr int OA2F = OA1F + DD * SZ_AH;
constexpr int OA2T = OA2F + DD * SZ_AH;
constexpr int OA1T = OA2T + DD * SZ_AH;
constexpr int OA0T = OA1T + DD * SZ_AH;
constexpr int WTOT = OA0T + DD * SZ_A0T;  // 163840 f16 = 320 KB
}

__device__ __forceinline__ unsigned int pku(float a, float b) {
    return __builtin_bit_cast(unsigned int, __builtin_amdgcn_cvt_pkrtz(a, b));
}
__device__ __forceinline__ h2t pmax(h2t a, h2t b) {
#if __has_builtin(__builtin_elementwise_max)
    return __builtin_elementwise_max(a, b);   // v_pk_max_f16
#else
    h2t r; r[0] = a[0] > b[0] ? a[0] : b[0]; r[1] = a[1] > b[1] ? a[1] : b[1];
    return r;
#endif
}
__device__ __forceinline__ float fdot2(h2t a, h2t b, float c) {
#if __has_builtin(__builtin_amdgcn_fdot2)
    return __builtin_amdgcn_fdot2(a, b, c, false);
#else
    return c + (float)a[0] * (float)b[0] + (float)a[1] * (float)b[1];
#endif
}

// Prepack weights into 32x32x16 per-lane A-fragments. Unchanged from round 13.
__global__ void setup_weights(const float* __restrict__ W0, const float* __restrict__ W1,
                              const float* __restrict__ W2, _Float16* __restrict__ wsp)
{
    for (int i = blockIdx.x * blockDim.x + threadIdx.x; i < WTOT;
         i += gridDim.x * blockDim.x) {
        float val;
        if (i < OA1F) {          // A0F: A[m=h][k=f], kc_cnt=2, K pad 17->32
            int j = i - OA0F, d = j / SZ_A0F, r = j % SZ_A0F;
            int mt = r / 1024, r2 = r % 1024, kc = r2 / 512, r3 = r2 % 512;
            int lane = r3 / 8, jj = r3 % 8;
            int m = 32 * mt + (lane & 31), k = kc * 16 + (lane >> 5) * 8 + jj;
            val = (k < FIN) ? W0[((size_t)d * HH + m) * FIN + k] : 0.0f;
        } else if (i < OA2F) {   // A1F
            int j = i - OA1F, d = j / SZ_AH, r = j % SZ_AH;
            int mt = r / 2048, r2 = r % 2048, kc = r2 / 512, r3 = r2 % 512;
            int lane = r3 / 8, jj = r3 % 8;
            int m = 32 * mt + (lane & 31), k = kc * 16 + (lane >> 5) * 8 + jj;
            val = W1[((size_t)d * HH + m) * HH + k];
        } else if (i < OA2T) {   // A2F
            int j = i - OA2F, d = j / SZ_AH, r = j % SZ_AH;
            int mt = r / 2048, r2 = r % 2048, kc = r2 / 512, r3 = r2 % 512;
            int lane = r3 / 8, jj = r3 % 8;
            int m = 32 * mt + (lane & 31), k = kc * 16 + (lane >> 5) * 8 + jj;
            val = W2[((size_t)d * HH + m) * HH + k];
        } else if (i < OA1T) {   // A2T: A[m=h'][k=g] = W2[d,k,m]
            int j = i - OA2T, d = j / SZ_AH, r = j % SZ_AH;
            int mt = r / 2048, r2 = r % 2048, kc = r2 / 512, r3 = r2 % 512;
            int lane = r3 / 8, jj = r3 % 8;
            int m = 32 * mt + (lane & 31), k = kc * 16 + (lane >> 5) * 8 + jj;
            val = W2[((size_t)d * HH + k) * HH + m];
        } else if (i < OA0T) {   // A1T: A[m=h][k=h'] = W1[d,k,m]
            int j = i - OA1T, d = j / SZ_AH, r = j % SZ_AH;
            int mt = r / 2048, r2 = r % 2048, kc = r2 / 512, r3 = r2 % 512;
            int lane = r3 / 8, jj = r3 % 8;
            int m = 32 * mt + (lane & 31), k = kc * 16 + (lane >> 5) * 8 + jj;
            val = W1[((size_t)d * HH + k) * HH + m];
        } else {                 // A0T: A[m=f][k=h] = W0[d,k,m], M pad 17->32
            int j = i - OA0T, d = j / SZ_A0T, r = j % SZ_A0T;
            int kc = r / 512, r3 = r % 512;
            int lane = r3 / 8, jj = r3 % 8;
            int m = lane & 31, k = kc * 16 + (lane >> 5) * 8 + jj;
            val = (m < FIN) ? W0[((size_t)d * HH + k) * FIN + m] : 0.0f;
        }
        wsp[i] = (_Float16)val;
    }
}

// Round-14: fully LDS-FREE. Inter-layer handoff C-layout -> B-fragment is a
// lane l <-> l+32 exchange (shfl_xor 32) + cndmask: the 32x32 C col (lane&31)
// equals the B col, and the needed h-slices live in the partner half-wave.
// Backward PReLU signs come from packed h' words kept in REGISTERS (hp0/hp1;
// identical (mt,g,hi2,col) mapping in forward/backward tiles). L0's B is
// built from each lane's own window row. Round-13 evidence: 26% occupancy
// was LDS-capped and the ds round-trip dominated the per-stage stall chain.
__global__ __launch_bounds__(256) void fused_mlp(
    const float* __restrict__ x,
    const float* __restrict__ b0, const float* __restrict__ a0,
    const float* __restrict__ b1, const float* __restrict__ a1,
    const float* __restrict__ b2, const float* __restrict__ a2,
    const float* __restrict__ W3, const float* __restrict__ b3,
    const _Float16* __restrict__ wsp,
    float* __restrict__ out, float* __restrict__ partials)
{
    const int b   = blockIdx.y;
    const int d   = blockIdx.z;
    const int tid = threadIdx.x;
    const int wv  = __builtin_amdgcn_readfirstlane(tid >> 6);  // 0..3
    const int t   = tid & 63;
    const int col = t & 31;          // window within strip (= C/D col, B n)
    const int hi2 = t >> 5;          // half-wave selector
    const int strip = blockIdx.x * 4 + wv;
    const int n   = strip * 32 + col;
    const bool nv = (n < NW);

    // ---- load own window row (both half-waves load the same row) ----
    uint4 q0, q1;
    float xl;
    {
        const int w = min(n, NW - 1);
        const float* xr = x + ((size_t)b * TT + w) * DD;
        f32x4 x0 = *(const f32x4*)(xr + 0);
        f32x4 x1 = *(const f32x4*)(xr + 4);
        f32x4 x2 = *(const f32x4*)(xr + 8);
        f32x4 x3 = *(const f32x4*)(xr + 12);
        xl = xr[2 * DD + d];
        q0.x = pku(x0[0], x0[1]); q0.y = pku(x0[2], x0[3]);
        q0.z = pku(x1[0], x1[1]); q0.w = pku(x1[2], x1[3]);
        q1.x = pku(x2[0], x2[1]); q1.y = pku(x2[2], x2[3]);
        q1.z = pku(x3[0], x3[1]); q1.w = pku(x3[2], x3[3]);
    }

    const float A0f = a0[d], A1f = a1[d], A2f = a2[d];
    const h2t apk0 = __builtin_bit_cast(h2t, pku(A0f, A0f));
    const h2t apk1 = __builtin_bit_cast(h2t, pku(A1f, A1f));
    const h2t apk2 = __builtin_bit_cast(h2t, pku(A2f, A2f));

    // C tiles: col = col, row h = 32*mt + 8*(reg>>2) + (reg&3) + 4*hi2
    f32x16 C[2];

    // Build a B-fragment (k = kc*16 + hi2*8 + j over rows h) from the packed
    // P-words of the h-pair (even g: h base+0..7-low, odd g: base+8..15).
    // Lane l<32 needs {own Pe, partner Pe}; lane l>=32 needs {partner Po, own Po}.
    auto mkB = [&](uint2 Pe, uint2 Po) -> half8 {
        unsigned V0 = hi2 ? Pe.x : Po.x;     // what my partner needs from me
        unsigned V1 = hi2 ? Pe.y : Po.y;
        unsigned s0 = __shfl_xor(V0, 32);
        unsigned s1 = __shfl_xor(V1, 32);
        uint4 u;
        u.x = hi2 ? s0 : Pe.x;
        u.y = hi2 ? s1 : Pe.y;
        u.z = hi2 ? Po.x : s0;
        u.w = hi2 ? Po.y : s1;
        return __builtin_bit_cast(half8, u);
    };

    auto zeroC = [&]() {
        #pragma unroll
        for (int mt = 0; mt < 2; ++mt)
            #pragma unroll
            for (int r = 0; r < 16; ++r) C[mt][r] = 0.0f;
    };
    auto biasInit = [&](const float* bp) {
        #pragma unroll
        for (int mt = 0; mt < 2; ++mt)
            #pragma unroll
            for (int g = 0; g < 4; ++g) {
                f32x4 bb = *(const f32x4*)(bp + 32 * mt + 8 * g + 4 * hi2);
                C[mt][4 * g + 0] = bb[0]; C[mt][4 * g + 1] = bb[1];
                C[mt][4 * g + 2] = bb[2]; C[mt][4 * g + 3] = bb[3];
            }
    };
    // K=64 GEMM with B built from P-words (kc -> mt_src = kc>>1, g = (kc&1)*2)
    auto gemmP = [&](const _Float16* apk, const uint2 (&P)[2][4]) {
        #pragma unroll
        for (int kc = 0; kc < 4; ++kc) {
            half8 Bv = mkB(P[kc >> 1][(kc & 1) * 2], P[kc >> 1][(kc & 1) * 2 + 1]);
            #pragma unroll
            for (int mt = 0; mt < 2; ++mt) {
                half8 a = *(const half8*)(apk + (size_t)((mt * 4 + kc) * 64 + t) * 8);
                C[mt] = __builtin_amdgcn_mfma_f32_32x32x16_f16(a, Bv, C[mt], 0, 0, 0);
            }
        }
    };
    // pack C -> packed PReLU -> P-words (registers; also the backward sign carrier)
    auto preluPack = [&](h2t ap, uint2 (&P)[2][4]) {
        #pragma unroll
        for (int mt = 0; mt < 2; ++mt)
            #pragma unroll
            for (int g = 0; g < 4; ++g) {
                unsigned lo_ = pku(C[mt][4 * g + 0], C[mt][4 * g + 1]);
                unsigned hi_ = pku(C[mt][4 * g + 2], C[mt][4 * g + 3]);
                h2t hl = __builtin_bit_cast(h2t, lo_);
                h2t hh = __builtin_bit_cast(h2t, hi_);
                hl = pmax(hl, hl * ap);
                hh = pmax(hh, hh * ap);
                P[mt][g].x = __builtin_bit_cast(unsigned int, hl);
                P[mt][g].y = __builtin_bit_cast(unsigned int, hh);
            }
    };
    // backward: v' = v * d, d from sign of h' words; write packed v' into V
    auto dApplyPack = [&](h2t ap, const uint2 (&H)[2][4], uint2 (&V)[2][4]) {
        #pragma unroll
        for (int mt = 0; mt < 2; ++mt)
            #pragma unroll
            for (int g = 0; g < 4; ++g) {
                unsigned vx = pku(C[mt][4 * g + 0], C[mt][4 * g + 1]);
                unsigned vy = pku(C[mt][4 * g + 2], C[mt][4 * g + 3]);
                unsigned avx = __builtin_bit_cast(unsigned int,
                                   __builtin_bit_cast(h2t, vx) * ap);
                unsigned avy = __builtin_bit_cast(unsigned int,
                                   __builtin_bit_cast(h2t, vy) * ap);
                unsigned mx = ((H[mt][g].x & 0x80008000u) >> 15) * 0xFFFFu;
                unsigned my = ((H[mt][g].y & 0x80008000u) >> 15) * 0xFFFFu;
                V[mt][g].x = (mx & avx) | (~mx & vx);
                V[mt][g].y = (my & avy) | (~my & vy);
            }
    };

    uint2 hp0[2][4], hp1[2][4], vp[2][4];

    // ================= forward =================
    // L0: K=32; B built from own window row (no exchange needed: both
    // half-waves hold the same window). kc=0: f0..7 / f8..15; kc=1: xl-pad.
    {
        const _Float16* apk = wsp + OA0F + (size_t)d * SZ_A0F;
        biasInit(b0 + d * HH);
        uint4 u0;
        u0.x = hi2 ? q1.x : q0.x; u0.y = hi2 ? q1.y : q0.y;
        u0.z = hi2 ? q1.z : q0.z; u0.w = hi2 ? q1.w : q0.w;
        half8 B0 = __builtin_bit_cast(half8, u0);
        uint4 u1;
        u1.x = hi2 ? 0u : pku(xl, 0.f); u1.y = 0u; u1.z = 0u; u1.w = 0u;
        half8 B1 = __builtin_bit_cast(half8, u1);
        #pragma unroll
        for (int mt = 0; mt < 2; ++mt) {
            half8 a0_ = *(const half8*)(apk + (size_t)((mt * 2 + 0) * 64 + t) * 8);
            C[mt] = __builtin_amdgcn_mfma_f32_32x32x16_f16(a0_, B0, C[mt], 0, 0, 0);
            half8 a1_ = *(const half8*)(apk + (size_t)((mt * 2 + 1) * 64 + t) * 8);
            C[mt] = __builtin_amdgcn_mfma_f32_32x32x16_f16(a1_, B1, C[mt], 0, 0, 0);
        }
    }
    preluPack(apk0, hp0);

    biasInit(b1 + d * HH);
    gemmP(wsp + OA1F + (size_t)d * SZ_AH, hp0);
    preluPack(apk1, hp1);

    biasInit(b2 + d * HH);
    gemmP(wsp + OA2F + (size_t)d * SZ_AH, hp1);

    // ---- h2 packed + residual dot + v2 init (all in registers) ----
    {
        uint2 w3p[2][4];
        float s = 0.0f;
        uint2 h2p[2][4];
        #pragma unroll
        for (int mt = 0; mt < 2; ++mt)
            #pragma unroll
            for (int g = 0; g < 4; ++g) {
                f32x4 w = *(const f32x4*)(W3 + d * HH + 32 * mt + 8 * g + 4 * hi2);
                w3p[mt][g].x = pku(w[0], w[1]);
                w3p[mt][g].y = pku(w[2], w[3]);
                unsigned lo_ = pku(C[mt][4 * g + 0], C[mt][4 * g + 1]);
                unsigned hi_ = pku(C[mt][4 * g + 2], C[mt][4 * g + 3]);
                h2t hl = __builtin_bit_cast(h2t, lo_);
                h2t hh = __builtin_bit_cast(h2t, hi_);
                hl = pmax(hl, hl * apk2);
                hh = pmax(hh, hh * apk2);
                h2p[mt][g].x = __builtin_bit_cast(unsigned int, hl);
                h2p[mt][g].y = __builtin_bit_cast(unsigned int, hh);
                s = fdot2(hl, __builtin_bit_cast(h2t, w3p[mt][g].x), s);
                s = fdot2(hh, __builtin_bit_cast(h2t, w3p[mt][g].y), s);
            }
        s += __shfl_xor(s, 32);   // combine the two h-halves
        if (hi2 == 0 && nv)
            out[RES_OFF + ((size_t)b * NW + n) * DD + d] = s + b3[d];

        // v2 = w3 * d2 (d2 from h2 sign) -> vp
        #pragma unroll
        for (int mt = 0; mt < 2; ++mt)
            #pragma unroll
            for (int g = 0; g < 4; ++g) {
                unsigned wax = __builtin_bit_cast(unsigned int,
                                   __builtin_bit_cast(h2t, w3p[mt][g].x) * apk2);
                unsigned way = __builtin_bit_cast(unsigned int,
                                   __builtin_bit_cast(h2t, w3p[mt][g].y) * apk2);
                unsigned mx = ((h2p[mt][g].x & 0x80008000u) >> 15) * 0xFFFFu;
                unsigned my = ((h2p[mt][g].y & 0x80008000u) >> 15) * 0xFFFFu;
                vp[mt][g].x = (mx & wax) | (~mx & w3p[mt][g].x);
                vp[mt][g].y = (my & way) | (~my & w3p[mt][g].y);
            }
    }

    // ================= backward =================
    zeroC();
    gemmP(wsp + OA2T + (size_t)d * SZ_AH, vp);   // v1 raw
    dApplyPack(apk1, hp1, vp);                   // vp = packed v1'

    zeroC();
    gemmP(wsp + OA1T + (size_t)d * SZ_AH, vp);   // v0 raw
    dApplyPack(apk0, hp0, vp);                   // vp = packed v0'

    // G = W0T @ v0 : single M=32 tile; f = (reg&3) + 8*(reg>>2) + 4*hi2
    f32x16 G;
    {
        #pragma unroll
        for (int r = 0; r < 16; ++r) G[r] = 0.0f;
        const _Float16* apk = wsp + OA0T + (size_t)d * SZ_A0T;
        #pragma unroll
        for (int kc = 0; kc < 4; ++kc) {
            half8 Bv = mkB(vp[kc >> 1][(kc & 1) * 2], vp[kc >> 1][(kc & 1) * 2 + 1]);
            half8 a = *(const half8*)(apk + (size_t)(kc * 64 + t) * 8);
            G = __builtin_amdgcn_mfma_f32_32x32x16_f16(a, Bv, G, 0, 0, 0);
        }
    }

    // hist_jac: groups g=0,1 cover f 0..15 (f_base = 8g + 4*hi2)
    if (nv) {
        #pragma unroll
        for (int g = 0; g < 2; ++g) {
            f32x4 v;
            v[0] = G[4 * g + 0]; v[1] = G[4 * g + 1];
            v[2] = G[4 * g + 2]; v[3] = G[4 * g + 3];
            *(f32x4*)(out + HJ_OFF + ((size_t)d * NTOT + (size_t)b * NW + n) * 16
                      + 8 * g + 4 * hi2) = v;
        }
    }

    // log|g[16]|: f=16 -> reg 8, hi2==0 lanes
    {
        float ld = (hi2 == 0 && nv) ? __logf(fabsf(G[8])) : 0.0f;
        #pragma unroll
        for (int off = 32; off > 0; off >>= 1) ld += __shfl_down(ld, off);
        if (t == 0) partials[(b * DD + d) * NSTR + strip] = ld;
    }
}

__global__ void reduce_log(const float* __restrict__ partials, float* __restrict__ out)
{
    const int b = blockIdx.x;     // BB blocks x 64 threads
    const int t = threadIdx.x;
    float s = 0.0f;
    #pragma unroll
    for (int i = 0; i < 4; ++i) s += partials[b * (DD * NSTR) + t * 4 + i];
    #pragma unroll
    for (int off = 32; off > 0; off >>= 1) s += __shfl_down(s, off);
    if (t == 0) out[LOG_OFF + b] = s;
}

extern "C" void kernel_launch(void* const* d_in, const int* in_sizes, int n_in,
                              void* d_out, int out_size, void* d_ws, size_t ws_size,
                              hipStream_t stream)
{
    const float* x  = (const float*)d_in[0];
    const float* W0 = (const float*)d_in[1];
    const float* b0 = (const float*)d_in[2];
    const float* a0 = (const float*)d_in[3];
    const float* W1 = (const float*)d_in[4];
    const float* b1 = (const float*)d_in[5];
    const float* a1 = (const float*)d_in[6];
    const float* W2 = (const float*)d_in[7];
    const float* b2 = (const float*)d_in[8];
    const float* a2 = (const float*)d_in[9];
    const float* W3 = (const float*)d_in[10];
    const float* b3 = (const float*)d_in[11];

    float*     out      = (float*)d_out;
    _Float16*  wsp      = (_Float16*)d_ws;
    float*     partials = (float*)((char*)d_ws + (size_t)WTOT * 2);  // 16384 floats

    setup_weights<<<160, 1024, 0, stream>>>(W0, W1, W2, wsp);

    dim3 grid(GXB, BB, DD);   // 8 x 64 x 8 = 4096 blocks x 4 independent waves
    fused_mlp<<<grid, 256, 0, stream>>>(x, b0, a0, b1, a1, b2, a2, W3, b3,
                                        wsp, out, partials);
    reduce_log<<<BB, 64, 0, stream>>>(partials, out);
}

// Round 15
// 71.100 us; speedup vs baseline: 1.0463x; 1.0463x over previous
//
#include <hip/hip_runtime.h>
#include <cmath>

typedef _Float16 half8 __attribute__((ext_vector_type(8)));
typedef _Float16 h2t   __attribute__((ext_vector_type(2)));
typedef float f32x4  __attribute__((ext_vector_type(4)));
typedef float f32x16 __attribute__((ext_vector_type(16)));

namespace {
constexpr int BB   = 64;
constexpr int TT   = 1002;
constexpr int DD   = 8;
constexpr int HH   = 64;
constexpr int LAGS = 2;
constexpr int NW   = TT - LAGS;      // 1000
constexpr int FIN  = LAGS * DD + 1;  // 17
constexpr int NTOT = BB * NW;        // 64000
constexpr int GXB  = 16;             // x-blocks; 2 waves/block; 32 windows/wave
constexpr int NSTR = 32;             // strips per (b,d)

constexpr int RES_OFF = 0;
constexpr int LOG_OFF = NTOT * DD;
constexpr int HJ_OFF  = LOG_OFF + BB;

// A-fragment pack for 32x32x16 MFMA (f16 units), layout verified in round 13:
// [mt][kc][lane 64][8]: m = 32*mt + (lane&31), k = kc*16 + (lane>>5)*8 + j.
constexpr int SZ_A0F = 2 * 2 * 64 * 8;   // M64 K32 (pad f>=17 -> 0)
constexpr int SZ_AH  = 2 * 4 * 64 * 8;   // M64 K64
constexpr int SZ_A0T = 1 * 4 * 64 * 8;   // M32 K64 (pad m>=17 -> 0)
constexpr int OA0F = 0;
constexpr int OA1F = OA0F + DD * SZ_A0F;
constexpr int OA2F = OA1F + DD * SZ_AH;
constexpr int OA2T = OA2F + DD * SZ_AH;
constexpr int OA1T = OA2T + DD * SZ_AH;
constexpr int OA0T = OA1T + DD * SZ_AH;
constexpr int WTOT = OA0T + DD * SZ_A0T;  // 163840 f16 = 320 KB

// LDS: ONE 4KB WORK region per wave (32 rows x 128 B). Stage sequence
// x -> h0' -> h1' -> v2 -> v1' -> v0' reuses it; same-wave DS in-order
// execution makes read-before-overwrite safe. Round-15: H0/H1 sign
// storage moved to registers (round-14 evidence) -> LDS/block 24KB -> 8KB.
constexpr int WV_STRIDE = 4096;
}

__device__ __forceinline__ unsigned int pku(float a, float b) {
    return __builtin_bit_cast(unsigned int, __builtin_amdgcn_cvt_pkrtz(a, b));
}
__device__ __forceinline__ h2t pmax(h2t a, h2t b) {
#if __has_builtin(__builtin_elementwise_max)
    return __builtin_elementwise_max(a, b);   // v_pk_max_f16
#else
    h2t r; r[0] = a[0] > b[0] ? a[0] : b[0]; r[1] = a[1] > b[1] ? a[1] : b[1];
    return r;
#endif
}
__device__ __forceinline__ float fdot2(h2t a, h2t b, float c) {
#if __has_builtin(__builtin_amdgcn_fdot2)
    return __builtin_amdgcn_fdot2(a, b, c, false);
#else
    return c + (float)a[0] * (float)b[0] + (float)a[1] * (float)b[1];
#endif
}

// Prepack weights into 32x32x16 per-lane A-fragments. Unchanged from round 13.
__global__ void setup_weights(const float* __restrict__ W0, const float* __restrict__ W1,
                              const float* __restrict__ W2, _Float16* __restrict__ wsp)
{
    for (int i = blockIdx.x * blockDim.x + threadIdx.x; i < WTOT;
         i += gridDim.x * blockDim.x) {
        float val;
        if (i < OA1F) {          // A0F: A[m=h][k=f], kc_cnt=2, K pad 17->32
            int j = i - OA0F, d = j / SZ_A0F, r = j % SZ_A0F;
            int mt = r / 1024, r2 = r % 1024, kc = r2 / 512, r3 = r2 % 512;
            int lane = r3 / 8, jj = r3 % 8;
            int m = 32 * mt + (lane & 31), k = kc * 16 + (lane >> 5) * 8 + jj;
            val = (k < FIN) ? W0[((size_t)d * HH + m) * FIN + k] : 0.0f;
        } else if (i < OA2F) {   // A1F
            int j = i - OA1F, d = j / SZ_AH, r = j % SZ_AH;
            int mt = r / 2048, r2 = r % 2048, kc = r2 / 512, r3 = r2 % 512;
            int lane = r3 / 8, jj = r3 % 8;
            int m = 32 * mt + (lane & 31), k = kc * 16 + (lane >> 5) * 8 + jj;
            val = W1[((size_t)d * HH + m) * HH + k];
        } else if (i < OA2T) {   // A2F
            int j = i - OA2F, d = j / SZ_AH, r = j % SZ_AH;
            int mt = r / 2048, r2 = r % 2048, kc = r2 / 512, r3 = r2 % 512;
            int lane = r3 / 8, jj = r3 % 8;
            int m = 32 * mt + (lane & 31), k = kc * 16 + (lane >> 5) * 8 + jj;
            val = W2[((size_t)d * HH + m) * HH + k];
        } else if (i < OA1T) {   // A2T: A[m=h'][k=g] = W2[d,k,m]
            int j = i - OA2T, d = j / SZ_AH, r = j % SZ_AH;
            int mt = r / 2048, r2 = r % 2048, kc = r2 / 512, r3 = r2 % 512;
            int lane = r3 / 8, jj = r3 % 8;
            int m = 32 * mt + (lane & 31), k = kc * 16 + (lane >> 5) * 8 + jj;
            val = W2[((size_t)d * HH + k) * HH + m];
        } else if (i < OA0T) {   // A1T: A[m=h][k=h'] = W1[d,k,m]
            int j = i - OA1T, d = j / SZ_AH, r = j % SZ_AH;
            int mt = r / 2048, r2 = r % 2048, kc = r2 / 512, r3 = r2 % 512;
            int lane = r3 / 8, jj = r3 % 8;
            int m = 32 * mt + (lane & 31), k = kc * 16 + (lane >> 5) * 8 + jj;
            val = W1[((size_t)d * HH + k) * HH + m];
        } else {                 // A0T: A[m=f][k=h] = W0[d,k,m], M pad 17->32
            int j = i - OA0T, d = j / SZ_A0T, r = j % SZ_A0T;
            int kc = r / 512, r3 = r % 512;
            int lane = r3 / 8, jj = r3 % 8;
            int m = lane & 31, k = kc * 16 + (lane >> 5) * 8 + jj;
            val = (m < FIN) ? W0[((size_t)d * HH + k) * FIN + m] : 0.0f;
        }
        wsp[i] = (_Float16)val;
    }
}

// Round-15: round-13 structure (best, 60us) with (a) sign words in REGISTERS
// (hp0/hp1, from round 14) and (b) a single reused 4KB WORK region ->
// 8KB LDS/block, occupancy cap lifted (was 26%, LDS-capped at 24KB).
__global__ __launch_bounds__(128) void fused_mlp(
    const float* __restrict__ x,
    const float* __restrict__ b0, const float* __restrict__ a0,
    const float* __restrict__ b1, const float* __restrict__ a1,
    const float* __restrict__ b2, const float* __restrict__ a2,
    const float* __restrict__ W3, const float* __restrict__ b3,
    const _Float16* __restrict__ wsp,
    float* __restrict__ out, float* __restrict__ partials)
{
    const int b   = blockIdx.y;
    const int d   = blockIdx.z;
    const int tid = threadIdx.x;
    const int wv  = __builtin_amdgcn_readfirstlane(tid >> 6);  // 0..1
    const int t   = tid & 63;
    const int col = t & 31;          // window within strip (= C/D col, B n)
    const int hi2 = t >> 5;          // k-group / row-group selector
    const int strip = blockIdx.x * 2 + wv;
    const int n   = strip * 32 + col;
    const bool nv = (n < NW);

    __shared__ __align__(16) unsigned char Xs[2 * WV_STRIDE];  // 8 KB
    unsigned char* Xw = Xs + wv * WV_STRIDE;

    const int swz   = (col & 7) << 4;
    const int rbase = col * 128;
    // B-frag read addrs: k = kc*16 + hi2*8 + j -> byte kc*32 + hi2*16
    int rd[4];
    #pragma unroll
    for (int kc = 0; kc < 4; ++kc)
        rd[kc] = rbase + ((kc * 32 + hi2 * 16) ^ swz);

    // ---- stage inputs into WORK rows (lanes hi2==0; row = col) ----
    if (hi2 == 0) {
        const int w = min(strip * 32 + col, NW - 1);
        const float* xr = x + ((size_t)b * TT + w) * DD;
        f32x4 x0 = *(const f32x4*)(xr + 0);
        f32x4 x1 = *(const f32x4*)(xr + 4);
        f32x4 x2 = *(const f32x4*)(xr + 8);
        f32x4 x3 = *(const f32x4*)(xr + 12);
        float xl = xr[2 * DD + d];
        uint4 q0, q1, qz, zz;
        q0.x = pku(x0[0], x0[1]); q0.y = pku(x0[2], x0[3]);
        q0.z = pku(x1[0], x1[1]); q0.w = pku(x1[2], x1[3]);
        q1.x = pku(x2[0], x2[1]); q1.y = pku(x2[2], x2[3]);
        q1.z = pku(x3[0], x3[1]); q1.w = pku(x3[2], x3[3]);
        qz.x = pku(xl, 0.f); qz.y = 0u; qz.z = 0u; qz.w = 0u;
        zz.x = 0u; zz.y = 0u; zz.z = 0u; zz.w = 0u;
        *(uint4*)&Xw[rbase + (0  ^ swz)] = q0;   // k 0..7
        *(uint4*)&Xw[rbase + (16 ^ swz)] = q1;   // k 8..15
        *(uint4*)&Xw[rbase + (32 ^ swz)] = qz;   // k 16..23 (xl + 0)
        *(uint4*)&Xw[rbase + (48 ^ swz)] = zz;   // k 24..31 (pad)
    }
    // no barrier: all traffic is same-row (lane l <-> l+32), same-wave in-order

    const float A0f = a0[d], A1f = a1[d], A2f = a2[d];
    const h2t apk0 = __builtin_bit_cast(h2t, pku(A0f, A0f));
    const h2t apk1 = __builtin_bit_cast(h2t, pku(A1f, A1f));
    const h2t apk2 = __builtin_bit_cast(h2t, pku(A2f, A2f));

    // C tiles: col = col, row h = 32*mt + 8*(reg>>2) + (reg&3) + 4*hi2
    f32x16 C[2];

    auto zeroC = [&]() {
        #pragma unroll
        for (int mt = 0; mt < 2; ++mt)
            #pragma unroll
            for (int r = 0; r < 16; ++r) C[mt][r] = 0.0f;
    };
    auto biasInit = [&](const float* bp) {
        #pragma unroll
        for (int mt = 0; mt < 2; ++mt)
            #pragma unroll
            for (int g = 0; g < 4; ++g) {
                f32x4 bb = *(const f32x4*)(bp + 32 * mt + 8 * g + 4 * hi2);
                C[mt][4 * g + 0] = bb[0]; C[mt][4 * g + 1] = bb[1];
                C[mt][4 * g + 2] = bb[2]; C[mt][4 * g + 3] = bb[3];
            }
    };
    // K=64 GEMM, B from WORK rows
    auto gemmK64 = [&](const _Float16* apk) {
        #pragma unroll
        for (int kc = 0; kc < 4; ++kc) {
            half8 Bv = *(const half8*)&Xw[rd[kc]];
            #pragma unroll
            for (int mt = 0; mt < 2; ++mt) {
                half8 a = *(const half8*)(apk + (size_t)((mt * 4 + kc) * 64 + t) * 8);
                C[mt] = __builtin_amdgcn_mfma_f32_32x32x16_f16(a, Bv, C[mt], 0, 0, 0);
            }
        }
    };
    // write byte offset for (mt,g): h = 32mt+8g+4hi2 -> byte 64mt+16g+8hi2
    auto wroff = [&](int mt, int g) {
        return rbase + (((64 * mt + 16 * g) ^ swz) + 8 * hi2);
    };
    // forward: pack -> packed PReLU -> store to WORK + keep words in P (regs)
    auto preluStoreKeep = [&](h2t ap, uint2 (&P)[2][4]) {
        #pragma unroll
        for (int mt = 0; mt < 2; ++mt)
            #pragma unroll
            for (int g = 0; g < 4; ++g) {
                unsigned lo_ = pku(C[mt][4 * g + 0], C[mt][4 * g + 1]);
                unsigned hi_ = pku(C[mt][4 * g + 2], C[mt][4 * g + 3]);
                h2t hl = __builtin_bit_cast(h2t, lo_);
                h2t hh = __builtin_bit_cast(h2t, hi_);
                hl = pmax(hl, hl * ap);
                hh = pmax(hh, hh * ap);
                uint2 p;
                p.x = __builtin_bit_cast(unsigned int, hl);
                p.y = __builtin_bit_cast(unsigned int, hh);
                P[mt][g] = p;
                *(uint2*)&Xw[wroff(mt, g)] = p;
            }
    };
    // backward: v' = v * d, d from sign of h' words held in REGISTERS; store WORK
    auto dApplyStore = [&](h2t ap, const uint2 (&H)[2][4]) {
        #pragma unroll
        for (int mt = 0; mt < 2; ++mt)
            #pragma unroll
            for (int g = 0; g < 4; ++g) {
                unsigned vx = pku(C[mt][4 * g + 0], C[mt][4 * g + 1]);
                unsigned vy = pku(C[mt][4 * g + 2], C[mt][4 * g + 3]);
                unsigned avx = __builtin_bit_cast(unsigned int,
                                   __builtin_bit_cast(h2t, vx) * ap);
                unsigned avy = __builtin_bit_cast(unsigned int,
                                   __builtin_bit_cast(h2t, vy) * ap);
                unsigned mx = ((H[mt][g].x & 0x80008000u) >> 15) * 0xFFFFu;
                unsigned my = ((H[mt][g].y & 0x80008000u) >> 15) * 0xFFFFu;
                uint2 p;
                p.x = (mx & avx) | (~mx & vx);
                p.y = (my & avy) | (~my & vy);
                *(uint2*)&Xw[wroff(mt, g)] = p;
            }
    };

    uint2 hp0[2][4], hp1[2][4];

    // ================= forward =================
    // L0: K=32 (kc 0..1), B = staged x
    {
        const _Float16* apk = wsp + OA0F + (size_t)d * SZ_A0F;
        biasInit(b0 + d * HH);
        #pragma unroll
        for (int kc = 0; kc < 2; ++kc) {
            half8 Bv = *(const half8*)&Xw[rd[kc]];
            #pragma unroll
            for (int mt = 0; mt < 2; ++mt) {
                half8 a = *(const half8*)(apk + (size_t)((mt * 2 + kc) * 64 + t) * 8);
                C[mt] = __builtin_amdgcn_mfma_f32_32x32x16_f16(a, Bv, C[mt], 0, 0, 0);
            }
        }
    }
    preluStoreKeep(apk0, hp0);   // h0' overwrites x (reads already issued)

    biasInit(b1 + d * HH);
    gemmK64(wsp + OA1F + (size_t)d * SZ_AH);
    preluStoreKeep(apk1, hp1);   // h1' overwrites h0'

    biasInit(b2 + d * HH);
    gemmK64(wsp + OA2F + (size_t)d * SZ_AH);

    // ---- h2 packed + residual dot + v2 init (v2 -> WORK) ----
    {
        uint2 h2p[2][4], w3p[2][4];
        float s = 0.0f;
        #pragma unroll
        for (int mt = 0; mt < 2; ++mt)
            #pragma unroll
            for (int g = 0; g < 4; ++g) {
                f32x4 w = *(const f32x4*)(W3 + d * HH + 32 * mt + 8 * g + 4 * hi2);
                w3p[mt][g].x = pku(w[0], w[1]);
                w3p[mt][g].y = pku(w[2], w[3]);
                unsigned lo_ = pku(C[mt][4 * g + 0], C[mt][4 * g + 1]);
                unsigned hi_ = pku(C[mt][4 * g + 2], C[mt][4 * g + 3]);
                h2t hl = __builtin_bit_cast(h2t, lo_);
                h2t hh = __builtin_bit_cast(h2t, hi_);
                hl = pmax(hl, hl * apk2);
                hh = pmax(hh, hh * apk2);
                h2p[mt][g].x = __builtin_bit_cast(unsigned int, hl);
                h2p[mt][g].y = __builtin_bit_cast(unsigned int, hh);
                s = fdot2(hl, __builtin_bit_cast(h2t, w3p[mt][g].x), s);
                s = fdot2(hh, __builtin_bit_cast(h2t, w3p[mt][g].y), s);
            }
        s += __shfl_xor(s, 32);   // combine the two h-halves (hi2 0/1)
        if (hi2 == 0 && nv)
            out[RES_OFF + ((size_t)b * NW + n) * DD + d] = s + b3[d];

        // v2 = w3 * d2 (d2 from h2 sign) -> WORK
        #pragma unroll
        for (int mt = 0; mt < 2; ++mt)
            #pragma unroll
            for (int g = 0; g < 4; ++g) {
                unsigned wax = __builtin_bit_cast(unsigned int,
                                   __builtin_bit_cast(h2t, w3p[mt][g].x) * apk2);
                unsigned way = __builtin_bit_cast(unsigned int,
                                   __builtin_bit_cast(h2t, w3p[mt][g].y) * apk2);
                unsigned mx = ((h2p[mt][g].x & 0x80008000u) >> 15) * 0xFFFFu;
                unsigned my = ((h2p[mt][g].y & 0x80008000u) >> 15) * 0xFFFFu;
                uint2 p;
                p.x = (mx & wax) | (~mx & w3p[mt][g].x);
                p.y = (my & way) | (~my & w3p[mt][g].y);
                *(uint2*)&Xw[wroff(mt, g)] = p;
            }
    }

    // ================= backward =================
    zeroC();
    gemmK64(wsp + OA2T + (size_t)d * SZ_AH);   // v1 raw (B = v2)
    dApplyStore(apk1, hp1);                    // v1' -> WORK

    zeroC();
    gemmK64(wsp + OA1T + (size_t)d * SZ_AH);   // v0 raw (B = v1')
    dApplyStore(apk0, hp0);                    // v0' -> WORK

    // G = W0T @ v0 : single M=32 tile; f = (reg&3) + 8*(reg>>2) + 4*hi2
    f32x16 G;
    {
        #pragma unroll
        for (int r = 0; r < 16; ++r) G[r] = 0.0f;
        const _Float16* apk = wsp + OA0T + (size_t)d * SZ_A0T;
        #pragma unroll
        for (int kc = 0; kc < 4; ++kc) {
            half8 Bv = *(const half8*)&Xw[rd[kc]];
            half8 a = *(const half8*)(apk + (size_t)(kc * 64 + t) * 8);
            G = __builtin_amdgcn_mfma_f32_32x32x16_f16(a, Bv, G, 0, 0, 0);
        }
    }

    // hist_jac: groups g=0,1 cover f 0..15 (f_base = 8g + 4*hi2)
    if (nv) {
        #pragma unroll
        for (int g = 0; g < 2; ++g) {
            f32x4 v;
            v[0] = G[4 * g + 0]; v[1] = G[4 * g + 1];
            v[2] = G[4 * g + 2]; v[3] = G[4 * g + 3];
            *(f32x4*)(out + HJ_OFF + ((size_t)d * NTOT + (size_t)b * NW + n) * 16
                      + 8 * g + 4 * hi2) = v;
        }
    }

    // log|g[16]|: f=16 -> reg 8, hi2==0 lanes
    {
        float ld = (hi2 == 0 && nv) ? __logf(fabsf(G[8])) : 0.0f;
        #pragma unroll
        for (int off = 32; off > 0; off >>= 1) ld += __shfl_down(ld, off);
        if (t == 0) partials[(b * DD + d) * NSTR + strip] = ld;
    }
}

__global__ void reduce_log(const float* __restrict__ partials, float* __restrict__ out)
{
    const int b = blockIdx.x;     // BB blocks x 64 threads
    const int t = threadIdx.x;
    float s = 0.0f;
    #pragma unroll
    for (int i = 0; i < 4; ++i) s += partials[b * (DD * NSTR) + t * 4 + i];
    #pragma unroll
    for (int off = 32; off > 0; off >>= 1) s += __shfl_down(s, off);
    if (t == 0) out[LOG_OFF + b] = s;
}

extern "C" void kernel_launch(void* const* d_in, const int* in_sizes, int n_in,
                              void* d_out, int out_size, void* d_ws, size_t ws_size,
                              hipStream_t stream)
{
    const float* x  = (const float*)d_in[0];
    const float* W0 = (const float*)d_in[1];
    const float* b0 = (const float*)d_in[2];
    const float* a0 = (const float*)d_in[3];
    const float* W1 = (const float*)d_in[4];
    const float* b1 = (const float*)d_in[5];
    const float* a1 = (const float*)d_in[6];
    const float* W2 = (const float*)d_in[7];
    const float* b2 = (const float*)d_in[8];
    const float* a2 = (const float*)d_in[9];
    const float* W3 = (const float*)d_in[10];
    const float* b3 = (const float*)d_in[11];

    float*     out      = (float*)d_out;
    _Float16*  wsp      = (_Float16*)d_ws;
    float*     partials = (float*)((char*)d_ws + (size_t)WTOT * 2);  // 16384 floats

    setup_weights<<<160, 1024, 0, stream>>>(W0, W1, W2, wsp);

    dim3 grid(GXB, BB, DD);   // 16 x 64 x 8 = 8192 blocks x 2 waves (32 win/wave)
    fused_mlp<<<grid, 128, 0, stream>>>(x, b0, a0, b1, a1, b2, a2, W3, b3,
                                        wsp, out, partials);
    reduce_log<<<BB, 64, 0, stream>>>(partials, out);
}

// Round 16
// 65.357 us; speedup vs baseline: 1.1382x; 1.0879x over previous
//
#include <hip/hip_runtime.h>
#include <cmath>

typedef _Float16 half8 __attribute__((ext_vector_type(8)));
typedef _Float16 h2t   __attribute__((ext_vector_type(2)));
typedef float f32x4  __attribute__((ext_vector_type(4)));
typedef float f32x16 __attribute__((ext_vector_type(16)));

namespace {
constexpr int BB   = 64;
constexpr int TT   = 1002;
constexpr int DD   = 8;
constexpr int HH   = 64;
constexpr int LAGS = 2;
constexpr int NW   = TT - LAGS;      // 1000
constexpr int FIN  = LAGS * DD + 1;  // 17
constexpr int NTOT = BB * NW;        // 64000
constexpr int GXB  = 16;             // x-blocks; 2 waves/block; 32 windows/wave
constexpr int NSTR = 32;             // strips per (b,d)

constexpr int RES_OFF = 0;
constexpr int LOG_OFF = NTOT * DD;
constexpr int HJ_OFF  = LOG_OFF + BB;

// A-fragment pack for 32x32x16 MFMA (f16 units), layout verified round 13:
// [mt][kc][lane 64][8]: m = 32*mt + (lane&31), k = kc*16 + (lane>>5)*8 + j.
constexpr int SZ_A0F = 2 * 2 * 64 * 8;   // M64 K32 (pad f>=17 -> 0)
constexpr int SZ_AH  = 2 * 4 * 64 * 8;   // M64 K64
constexpr int SZ_A0T = 1 * 4 * 64 * 8;   // M32 K64 (pad m>=17 -> 0)
constexpr int OA0F = 0;
constexpr int OA1F = OA0F + DD * SZ_A0F;
constexpr int OA2F = OA1F + DD * SZ_AH;
constexpr int OA2T = OA2F + DD * SZ_AH;
constexpr int OA1T = OA2T + DD * SZ_AH;
constexpr int OA0T = OA1T + DD * SZ_AH;
constexpr int WTOT = OA0T + DD * SZ_A0T;  // 163840 f16 = 320 KB

// LDS: per wave 3 regions (WORK | H0 | H1) x 32 rows x 128 B = 12 KB
// (round-13 layout, empirically best of rounds 13/14/15)
constexpr int REG_H0   = 4096;
constexpr int REG_H1   = 8192;
constexpr int WV_STRIDE = 12288;
}

__device__ __forceinline__ unsigned int pku(float a, float b) {
    return __builtin_bit_cast(unsigned int, __builtin_amdgcn_cvt_pkrtz(a, b));
}
__device__ __forceinline__ h2t pmax(h2t a, h2t b) {
#if __has_builtin(__builtin_elementwise_max)
    return __builtin_elementwise_max(a, b);   // v_pk_max_f16
#else
    h2t r; r[0] = a[0] > b[0] ? a[0] : b[0]; r[1] = a[1] > b[1] ? a[1] : b[1];
    return r;
#endif
}
__device__ __forceinline__ float fdot2(h2t a, h2t b, float c) {
#if __has_builtin(__builtin_amdgcn_fdot2)
    return __builtin_amdgcn_fdot2(a, b, c, false);
#else
    return c + (float)a[0] * (float)b[0] + (float)a[1] * (float)b[1];
#endif
}

// Prepack weights into 32x32x16 per-lane A-fragments. Unchanged from round 13.
__global__ void setup_weights(const float* __restrict__ W0, const float* __restrict__ W1,
                              const float* __restrict__ W2, _Float16* __restrict__ wsp)
{
    for (int i = blockIdx.x * blockDim.x + threadIdx.x; i < WTOT;
         i += gridDim.x * blockDim.x) {
        float val;
        if (i < OA1F) {          // A0F: A[m=h][k=f], kc_cnt=2, K pad 17->32
            int j = i - OA0F, d = j / SZ_A0F, r = j % SZ_A0F;
            int mt = r / 1024, r2 = r % 1024, kc = r2 / 512, r3 = r2 % 512;
            int lane = r3 / 8, jj = r3 % 8;
            int m = 32 * mt + (lane & 31), k = kc * 16 + (lane >> 5) * 8 + jj;
            val = (k < FIN) ? W0[((size_t)d * HH + m) * FIN + k] : 0.0f;
        } else if (i < OA2F) {   // A1F
            int j = i - OA1F, d = j / SZ_AH, r = j % SZ_AH;
            int mt = r / 2048, r2 = r % 2048, kc = r2 / 512, r3 = r2 % 512;
            int lane = r3 / 8, jj = r3 % 8;
            int m = 32 * mt + (lane & 31), k = kc * 16 + (lane >> 5) * 8 + jj;
            val = W1[((size_t)d * HH + m) * HH + k];
        } else if (i < OA2T) {   // A2F
            int j = i - OA2F, d = j / SZ_AH, r = j % SZ_AH;
            int mt = r / 2048, r2 = r % 2048, kc = r2 / 512, r3 = r2 % 512;
            int lane = r3 / 8, jj = r3 % 8;
            int m = 32 * mt + (lane & 31), k = kc * 16 + (lane >> 5) * 8 + jj;
            val = W2[((size_t)d * HH + m) * HH + k];
        } else if (i < OA1T) {   // A2T: A[m=h'][k=g] = W2[d,k,m]
            int j = i - OA2T, d = j / SZ_AH, r = j % SZ_AH;
            int mt = r / 2048, r2 = r % 2048, kc = r2 / 512, r3 = r2 % 512;
            int lane = r3 / 8, jj = r3 % 8;
            int m = 32 * mt + (lane & 31), k = kc * 16 + (lane >> 5) * 8 + jj;
            val = W2[((size_t)d * HH + k) * HH + m];
        } else if (i < OA0T) {   // A1T: A[m=h][k=h'] = W1[d,k,m]
            int j = i - OA1T, d = j / SZ_AH, r = j % SZ_AH;
            int mt = r / 2048, r2 = r % 2048, kc = r2 / 512, r3 = r2 % 512;
            int lane = r3 / 8, jj = r3 % 8;
            int m = 32 * mt + (lane & 31), k = kc * 16 + (lane >> 5) * 8 + jj;
            val = W1[((size_t)d * HH + k) * HH + m];
        } else {                 // A0T: A[m=f][k=h] = W0[d,k,m], M pad 17->32
            int j = i - OA0T, d = j / SZ_A0T, r = j % SZ_A0T;
            int kc = r / 512, r3 = r % 512;
            int lane = r3 / 8, jj = r3 % 8;
            int m = lane & 31, k = kc * 16 + (lane >> 5) * 8 + jj;
            val = (m < FIN) ? W0[((size_t)d * HH + k) * FIN + m] : 0.0f;
        }
        wsp[i] = (_Float16)val;
    }
}

// Round-16: round-13 structure (best, 60us) + software-pipelined A-fragments:
// two register buffers Aa/Ab; stage i+1's 8 A-frag loads issue while stage i
// computes from the other buffer, hiding the ~250cy L2 latency that headed
// every stage. Everything else identical to round 13.
__global__ __launch_bounds__(128) void fused_mlp(
    const float* __restrict__ x,
    const float* __restrict__ b0, const float* __restrict__ a0,
    const float* __restrict__ b1, const float* __restrict__ a1,
    const float* __restrict__ b2, const float* __restrict__ a2,
    const float* __restrict__ W3, const float* __restrict__ b3,
    const _Float16* __restrict__ wsp,
    float* __restrict__ out, float* __restrict__ partials)
{
    const int b   = blockIdx.y;
    const int d   = blockIdx.z;
    const int tid = threadIdx.x;
    const int wv  = __builtin_amdgcn_readfirstlane(tid >> 6);  // 0..1
    const int t   = tid & 63;
    const int col = t & 31;          // window within strip (= C/D col, B n)
    const int hi2 = t >> 5;          // k-group / row-group selector
    const int strip = blockIdx.x * 2 + wv;
    const int n   = strip * 32 + col;
    const bool nv = (n < NW);

    __shared__ __align__(16) unsigned char Xs[2 * WV_STRIDE];  // 24 KB
    unsigned char* Xw = Xs + wv * WV_STRIDE;

    const int swz   = (col & 7) << 4;
    const int rbase = col * 128;
    // B-frag read addrs (WORK-relative): k = kc*16 + hi2*8 + j -> byte kc*32+hi2*16
    int rd[4];
    #pragma unroll
    for (int kc = 0; kc < 4; ++kc)
        rd[kc] = rbase + ((kc * 32 + hi2 * 16) ^ swz);

    // ---- A-fragment prefetch buffers ----
    half8 Aa[8], Ab[8];
    auto loadA4 = [&](half8* dst, const _Float16* apk) {
        #pragma unroll
        for (int q = 0; q < 4; ++q)
            dst[q] = *(const half8*)(apk + (size_t)(q * 64 + t) * 8);
    };
    auto loadA8 = [&](half8* dst, const _Float16* apk) {
        #pragma unroll
        for (int q = 0; q < 8; ++q)
            dst[q] = *(const half8*)(apk + (size_t)(q * 64 + t) * 8);
    };

    // issue L0 + L1 fragment loads before staging (maximum lead time)
    loadA4(Aa, wsp + OA0F + (size_t)d * SZ_A0F);
    loadA8(Ab, wsp + OA1F + (size_t)d * SZ_AH);

    // ---- stage inputs into WORK rows (lanes hi2==0; row = col) ----
    if (hi2 == 0) {
        const int w = min(strip * 32 + col, NW - 1);
        const float* xr = x + ((size_t)b * TT + w) * DD;
        f32x4 x0 = *(const f32x4*)(xr + 0);
        f32x4 x1 = *(const f32x4*)(xr + 4);
        f32x4 x2 = *(const f32x4*)(xr + 8);
        f32x4 x3 = *(const f32x4*)(xr + 12);
        float xl = xr[2 * DD + d];
        uint4 q0, q1, qz, zz;
        q0.x = pku(x0[0], x0[1]); q0.y = pku(x0[2], x0[3]);
        q0.z = pku(x1[0], x1[1]); q0.w = pku(x1[2], x1[3]);
        q1.x = pku(x2[0], x2[1]); q1.y = pku(x2[2], x2[3]);
        q1.z = pku(x3[0], x3[1]); q1.w = pku(x3[2], x3[3]);
        qz.x = pku(xl, 0.f); qz.y = 0u; qz.z = 0u; qz.w = 0u;
        zz.x = 0u; zz.y = 0u; zz.z = 0u; zz.w = 0u;
        *(uint4*)&Xw[rbase + (0  ^ swz)] = q0;   // k 0..7
        *(uint4*)&Xw[rbase + (16 ^ swz)] = q1;   // k 8..15
        *(uint4*)&Xw[rbase + (32 ^ swz)] = qz;   // k 16..23 (xl + 0)
        *(uint4*)&Xw[rbase + (48 ^ swz)] = zz;   // k 24..31 (pad)
    }
    // no fence: same-wave DS ordering; compiler inserts lgkmcnt waits

    const float A0f = a0[d], A1f = a1[d], A2f = a2[d];
    const h2t apk0 = __builtin_bit_cast(h2t, pku(A0f, A0f));
    const h2t apk1 = __builtin_bit_cast(h2t, pku(A1f, A1f));
    const h2t apk2 = __builtin_bit_cast(h2t, pku(A2f, A2f));

    // C tiles: col = col, row h = 32*mt + 8*(reg>>2) + (reg&3) + 4*hi2
    f32x16 C[2];

    auto zeroC = [&]() {
        #pragma unroll
        for (int mt = 0; mt < 2; ++mt)
            #pragma unroll
            for (int r = 0; r < 16; ++r) C[mt][r] = 0.0f;
    };
    auto biasInit = [&](const float* bp) {
        #pragma unroll
        for (int mt = 0; mt < 2; ++mt)
            #pragma unroll
            for (int g = 0; g < 4; ++g) {
                f32x4 bb = *(const f32x4*)(bp + 32 * mt + 8 * g + 4 * hi2);
                C[mt][4 * g + 0] = bb[0]; C[mt][4 * g + 1] = bb[1];
                C[mt][4 * g + 2] = bb[2]; C[mt][4 * g + 3] = bb[3];
            }
    };
    // K=64 GEMM from prefetched A regs (index mt*4+kc), B from region `regoff`
    auto gemmR = [&](const half8* A, int regoff) {
        #pragma unroll
        for (int kc = 0; kc < 4; ++kc) {
            half8 Bv = *(const half8*)&Xw[rd[kc] + regoff];
            #pragma unroll
            for (int mt = 0; mt < 2; ++mt)
                C[mt] = __builtin_amdgcn_mfma_f32_32x32x16_f16(A[mt * 4 + kc], Bv, C[mt], 0, 0, 0);
        }
    };
    // write byte offset for (mt,g): h = 32mt+8g+4hi2 -> byte 64mt+16g+8hi2
    auto wroff = [&](int mt, int g) {
        return rbase + (((64 * mt + 16 * g) ^ swz) + 8 * hi2);
    };
    // forward: pack -> packed PReLU -> store to region
    auto preluStore = [&](h2t ap, int regoff) {
        #pragma unroll
        for (int mt = 0; mt < 2; ++mt)
            #pragma unroll
            for (int g = 0; g < 4; ++g) {
                unsigned lo_ = pku(C[mt][4 * g + 0], C[mt][4 * g + 1]);
                unsigned hi_ = pku(C[mt][4 * g + 2], C[mt][4 * g + 3]);
                h2t hl = __builtin_bit_cast(h2t, lo_);
                h2t hh = __builtin_bit_cast(h2t, hi_);
                hl = pmax(hl, hl * ap);
                hh = pmax(hh, hh * ap);
                uint2 p;
                p.x = __builtin_bit_cast(unsigned int, hl);
                p.y = __builtin_bit_cast(unsigned int, hh);
                *(uint2*)&Xw[wroff(mt, g) + regoff] = p;
            }
    };
    // backward: v' = v * d, d from sign of h' read from `hregoff`; store WORK
    auto dApplyStore = [&](h2t ap, int hregoff) {
        #pragma unroll
        for (int mt = 0; mt < 2; ++mt)
            #pragma unroll
            for (int g = 0; g < 4; ++g) {
                const int off = wroff(mt, g);
                uint2 hr = *(const uint2*)&Xw[off + hregoff];
                unsigned vx = pku(C[mt][4 * g + 0], C[mt][4 * g + 1]);
                unsigned vy = pku(C[mt][4 * g + 2], C[mt][4 * g + 3]);
                unsigned avx = __builtin_bit_cast(unsigned int,
                                   __builtin_bit_cast(h2t, vx) * ap);
                unsigned avy = __builtin_bit_cast(unsigned int,
                                   __builtin_bit_cast(h2t, vy) * ap);
                unsigned mx = ((hr.x & 0x80008000u) >> 15) * 0xFFFFu;
                unsigned my = ((hr.y & 0x80008000u) >> 15) * 0xFFFFu;
                uint2 p;
                p.x = (mx & avx) | (~mx & vx);
                p.y = (my & avy) | (~my & vy);
                *(uint2*)&Xw[off] = p;
            }
    };

    // ================= forward =================
    // L0: K=32 (kc 0..1), A = Aa[mt*2+kc]
    {
        biasInit(b0 + d * HH);
        #pragma unroll
        for (int kc = 0; kc < 2; ++kc) {
            half8 Bv = *(const half8*)&Xw[rd[kc]];
            #pragma unroll
            for (int mt = 0; mt < 2; ++mt)
                C[mt] = __builtin_amdgcn_mfma_f32_32x32x16_f16(Aa[mt * 2 + kc], Bv, C[mt], 0, 0, 0);
        }
    }
    preluStore(apk0, REG_H0);
    loadA8(Aa, wsp + OA2F + (size_t)d * SZ_AH);   // prefetch L2

    biasInit(b1 + d * HH);
    gemmR(Ab, REG_H0);                            // L1
    preluStore(apk1, REG_H1);
    loadA8(Ab, wsp + OA2T + (size_t)d * SZ_AH);   // prefetch T2

    biasInit(b2 + d * HH);
    gemmR(Aa, REG_H1);                            // L2

    // ---- h2 packed + residual dot + v2 init (v2 -> WORK) ----
    {
        uint2 h2p[2][4], w3p[2][4];
        float s = 0.0f;
        #pragma unroll
        for (int mt = 0; mt < 2; ++mt)
            #pragma unroll
            for (int g = 0; g < 4; ++g) {
                f32x4 w = *(const f32x4*)(W3 + d * HH + 32 * mt + 8 * g + 4 * hi2);
                w3p[mt][g].x = pku(w[0], w[1]);
                w3p[mt][g].y = pku(w[2], w[3]);
                unsigned lo_ = pku(C[mt][4 * g + 0], C[mt][4 * g + 1]);
                unsigned hi_ = pku(C[mt][4 * g + 2], C[mt][4 * g + 3]);
                h2t hl = __builtin_bit_cast(h2t, lo_);
                h2t hh = __builtin_bit_cast(h2t, hi_);
                hl = pmax(hl, hl * apk2);
                hh = pmax(hh, hh * apk2);
                h2p[mt][g].x = __builtin_bit_cast(unsigned int, hl);
                h2p[mt][g].y = __builtin_bit_cast(unsigned int, hh);
                s = fdot2(hl, __builtin_bit_cast(h2t, w3p[mt][g].x), s);
                s = fdot2(hh, __builtin_bit_cast(h2t, w3p[mt][g].y), s);
            }
        s += __shfl_xor(s, 32);   // combine the two h-halves (hi2 0/1)
        if (hi2 == 0 && nv)
            out[RES_OFF + ((size_t)b * NW + n) * DD + d] = s + b3[d];

        // v2 = w3 * d2 (d2 from h2 sign) -> WORK
        #pragma unroll
        for (int mt = 0; mt < 2; ++mt)
            #pragma unroll
            for (int g = 0; g < 4; ++g) {
                unsigned wax = __builtin_bit_cast(unsigned int,
                                   __builtin_bit_cast(h2t, w3p[mt][g].x) * apk2);
                unsigned way = __builtin_bit_cast(unsigned int,
                                   __builtin_bit_cast(h2t, w3p[mt][g].y) * apk2);
                unsigned mx = ((h2p[mt][g].x & 0x80008000u) >> 15) * 0xFFFFu;
                unsigned my = ((h2p[mt][g].y & 0x80008000u) >> 15) * 0xFFFFu;
                uint2 p;
                p.x = (mx & wax) | (~mx & w3p[mt][g].x);
                p.y = (my & way) | (~my & w3p[mt][g].y);
                *(uint2*)&Xw[wroff(mt, g)] = p;
            }
    }
    loadA8(Aa, wsp + OA1T + (size_t)d * SZ_AH);   // prefetch T1

    // ================= backward =================
    zeroC();
    gemmR(Ab, 0);                                 // T2 (B = v2)
    dApplyStore(apk1, REG_H1);                    // v1' -> WORK
    loadA4(Ab, wsp + OA0T + (size_t)d * SZ_A0T);  // prefetch G

    zeroC();
    gemmR(Aa, 0);                                 // T1 (B = v1')
    dApplyStore(apk0, REG_H0);                    // v0' -> WORK

    // G = W0T @ v0 : single M=32 tile; f = (reg&3) + 8*(reg>>2) + 4*hi2
    f32x16 G;
    {
        #pragma unroll
        for (int r = 0; r < 16; ++r) G[r] = 0.0f;
        #pragma unroll
        for (int kc = 0; kc < 4; ++kc) {
            half8 Bv = *(const half8*)&Xw[rd[kc]];
            G = __builtin_amdgcn_mfma_f32_32x32x16_f16(Ab[kc], Bv, G, 0, 0, 0);
        }
    }

    // hist_jac: groups g=0,1 cover f 0..15 (f_base = 8g + 4*hi2)
    if (nv) {
        #pragma unroll
        for (int g = 0; g < 2; ++g) {
            f32x4 v;
            v[0] = G[4 * g + 0]; v[1] = G[4 * g + 1];
            v[2] = G[4 * g + 2]; v[3] = G[4 * g + 3];
            *(f32x4*)(out + HJ_OFF + ((size_t)d * NTOT + (size_t)b * NW + n) * 16
                      + 8 * g + 4 * hi2) = v;
        }
    }

    // log|g[16]|: f=16 -> reg 8, hi2==0 lanes
    {
        float ld = (hi2 == 0 && nv) ? __logf(fabsf(G[8])) : 0.0f;
        #pragma unroll
        for (int off = 32; off > 0; off >>= 1) ld += __shfl_down(ld, off);
        if (t == 0) partials[(b * DD + d) * NSTR + strip] = ld;
    }
}

__global__ void reduce_log(const float* __restrict__ partials, float* __restrict__ out)
{
    const int b = blockIdx.x;     // BB blocks x 64 threads
    const int t = threadIdx.x;
    float s = 0.0f;
    #pragma unroll
    for (int i = 0; i < 4; ++i) s += partials[b * (DD * NSTR) + t * 4 + i];
    #pragma unroll
    for (int off = 32; off > 0; off >>= 1) s += __shfl_down(s, off);
    if (t == 0) out[LOG_OFF + b] = s;
}

extern "C" void kernel_launch(void* const* d_in, const int* in_sizes, int n_in,
                              void* d_out, int out_size, void* d_ws, size_t ws_size,
                              hipStream_t stream)
{
    const float* x  = (const float*)d_in[0];
    const float* W0 = (const float*)d_in[1];
    const float* b0 = (const float*)d_in[2];
    const float* a0 = (const float*)d_in[3];
    const float* W1 = (const float*)d_in[4];
    const float* b1 = (const float*)d_in[5];
    const float* a1 = (const float*)d_in[6];
    const float* W2 = (const float*)d_in[7];
    const float* b2 = (const float*)d_in[8];
    const float* a2 = (const float*)d_in[9];
    const float* W3 = (const float*)d_in[10];
    const float* b3 = (const float*)d_in[11];

    float*     out      = (float*)d_out;
    _Float16*  wsp      = (_Float16*)d_ws;
    float*     partials = (float*)((char*)d_ws + (size_t)WTOT * 2);  // 16384 floats

    setup_weights<<<160, 1024, 0, stream>>>(W0, W1, W2, wsp);

    dim3 grid(GXB, BB, DD);   // 16 x 64 x 8 = 8192 blocks x 2 waves (32 win/wave)
    fused_mlp<<<grid, 128, 0, stream>>>(x, b0, a0, b1, a1, b2, a2, W3, b3,
                                        wsp, out, partials);
    reduce_log<<<BB, 64, 0, stream>>>(partials, out);
}

// Round 17
// 62.215 us; speedup vs baseline: 1.1957x; 1.0505x over previous
//
#include <hip/hip_runtime.h>
#include <cmath>

typedef _Float16 half8 __attribute__((ext_vector_type(8)));
typedef _Float16 h2t   __attribute__((ext_vector_type(2)));
typedef float f32x4  __attribute__((ext_vector_type(4)));
typedef float f32x16 __attribute__((ext_vector_type(16)));

namespace {
constexpr int BB   = 64;
constexpr int TT   = 1002;
constexpr int DD   = 8;
constexpr int HH   = 64;
constexpr int LAGS = 2;
constexpr int NW   = TT - LAGS;      // 1000
constexpr int FIN  = LAGS * DD + 1;  // 17
constexpr int NTOT = BB * NW;        // 64000
constexpr int GXB  = 16;             // x-blocks; 2 waves/block; 32 windows/wave
constexpr int NSTR = 32;             // strips per (b,d)

constexpr int RES_OFF = 0;
constexpr int LOG_OFF = NTOT * DD;
constexpr int HJ_OFF  = LOG_OFF + BB;

// A-fragment pack for 32x32x16 MFMA (f16 units).
// Frag layout [mt][kc][lane 64][8]: m = 32*mt + (lane&31),
// k = kc*16 + (lane>>5)*8 + j.
constexpr int SZ_A0F = 2 * 2 * 64 * 8;   // M64 K32 (pad f>=17 -> 0)
constexpr int SZ_AH  = 2 * 4 * 64 * 8;   // M64 K64
constexpr int SZ_A0T = 1 * 4 * 64 * 8;   // M32 K64 (pad m>=17 -> 0)
constexpr int OA0F = 0;
constexpr int OA1F = OA0F + DD * SZ_A0F;
constexpr int OA2F = OA1F + DD * SZ_AH;
constexpr int OA2T = OA2F + DD * SZ_AH;
constexpr int OA1T = OA2T + DD * SZ_AH;
constexpr int OA0T = OA1T + DD * SZ_AH;
constexpr int WTOT = OA0T + DD * SZ_A0T;  // 163840 f16 = 320 KB

// LDS: per wave 3 regions (WORK | H0 | H1) x 32 rows x 128 B = 12 KB
constexpr int REG_H0   = 4096;
constexpr int REG_H1   = 8192;
constexpr int WV_STRIDE = 12288;
}

__device__ __forceinline__ unsigned int pku(float a, float b) {
    return __builtin_bit_cast(unsigned int, __builtin_amdgcn_cvt_pkrtz(a, b));
}
__device__ __forceinline__ h2t pmax(h2t a, h2t b) {
#if __has_builtin(__builtin_elementwise_max)
    return __builtin_elementwise_max(a, b);   // v_pk_max_f16
#else
    h2t r; r[0] = a[0] > b[0] ? a[0] : b[0]; r[1] = a[1] > b[1] ? a[1] : b[1];
    return r;
#endif
}
__device__ __forceinline__ float fdot2(h2t a, h2t b, float c) {
#if __has_builtin(__builtin_amdgcn_fdot2)
    return __builtin_amdgcn_fdot2(a, b, c, false);
#else
    return c + (float)a[0] * (float)b[0] + (float)a[1] * (float)b[1];
#endif
}

// Prepack weights into 32x32x16 per-lane A-fragments.
__global__ void setup_weights(const float* __restrict__ W0, const float* __restrict__ W1,
                              const float* __restrict__ W2, _Float16* __restrict__ wsp)
{
    for (int i = blockIdx.x * blockDim.x + threadIdx.x; i < WTOT;
         i += gridDim.x * blockDim.x) {
        float val;
        if (i < OA1F) {          // A0F: A[m=h][k=f], kc_cnt=2, K pad 17->32
            int j = i - OA0F, d = j / SZ_A0F, r = j % SZ_A0F;
            int mt = r / 1024, r2 = r % 1024, kc = r2 / 512, r3 = r2 % 512;
            int lane = r3 / 8, jj = r3 % 8;
            int m = 32 * mt + (lane & 31), k = kc * 16 + (lane >> 5) * 8 + jj;
            val = (k < FIN) ? W0[((size_t)d * HH + m) * FIN + k] : 0.0f;
        } else if (i < OA2F) {   // A1F
            int j = i - OA1F, d = j / SZ_AH, r = j % SZ_AH;
            int mt = r / 2048, r2 = r % 2048, kc = r2 / 512, r3 = r2 % 512;
            int lane = r3 / 8, jj = r3 % 8;
            int m = 32 * mt + (lane & 31), k = kc * 16 + (lane >> 5) * 8 + jj;
            val = W1[((size_t)d * HH + m) * HH + k];
        } else if (i < OA2T) {   // A2F
            int j = i - OA2F, d = j / SZ_AH, r = j % SZ_AH;
            int mt = r / 2048, r2 = r % 2048, kc = r2 / 512, r3 = r2 % 512;
            int lane = r3 / 8, jj = r3 % 8;
            int m = 32 * mt + (lane & 31), k = kc * 16 + (lane >> 5) * 8 + jj;
            val = W2[((size_t)d * HH + m) * HH + k];
        } else if (i < OA1T) {   // A2T: A[m=h'][k=g] = W2[d,k,m]
            int j = i - OA2T, d = j / SZ_AH, r = j % SZ_AH;
            int mt = r / 2048, r2 = r % 2048, kc = r2 / 512, r3 = r2 % 512;
            int lane = r3 / 8, jj = r3 % 8;
            int m = 32 * mt + (lane & 31), k = kc * 16 + (lane >> 5) * 8 + jj;
            val = W2[((size_t)d * HH + k) * HH + m];
        } else if (i < OA0T) {   // A1T: A[m=h][k=h'] = W1[d,k,m]
            int j = i - OA1T, d = j / SZ_AH, r = j % SZ_AH;
            int mt = r / 2048, r2 = r % 2048, kc = r2 / 512, r3 = r2 % 512;
            int lane = r3 / 8, jj = r3 % 8;
            int m = 32 * mt + (lane & 31), k = kc * 16 + (lane >> 5) * 8 + jj;
            val = W1[((size_t)d * HH + k) * HH + m];
        } else {                 // A0T: A[m=f][k=h] = W0[d,k,m], M pad 17->32
            int j = i - OA0T, d = j / SZ_A0T, r = j % SZ_A0T;
            int kc = r / 512, r3 = r % 512;
            int lane = r3 / 8, jj = r3 % 8;
            int m = lane & 31, k = kc * 16 + (lane >> 5) * 8 + jj;
            val = (m < FIN) ? W0[((size_t)d * HH + k) * FIN + m] : 0.0f;
        }
        wsp[i] = (_Float16)val;
    }
}

// Round-17 = round-13 verbatim (empirical optimum, 60.0us). Rounds 14-16
// bracketed it: shfl handoff (-16%), register signs + 8KB LDS (-15%),
// A-prefetch (-8%) all regressed -> this structure is the plateau.
// 32x32x16 MFMA, 32 windows/wave; wave-private 12KB LDS (WORK|H0|H1);
// barrier-free; minimal-VALU epilogues (pkrtz/pk_max/sign-bfi).
__global__ __launch_bounds__(128) void fused_mlp(
    const float* __restrict__ x,
    const float* __restrict__ b0, const float* __restrict__ a0,
    const float* __restrict__ b1, const float* __restrict__ a1,
    const float* __restrict__ b2, const float* __restrict__ a2,
    const float* __restrict__ W3, const float* __restrict__ b3,
    const _Float16* __restrict__ wsp,
    float* __restrict__ out, float* __restrict__ partials)
{
    const int b   = blockIdx.y;
    const int d   = blockIdx.z;
    const int tid = threadIdx.x;
    const int wv  = __builtin_amdgcn_readfirstlane(tid >> 6);  // 0..1
    const int t   = tid & 63;
    const int col = t & 31;          // window within strip (= C/D col, B n)
    const int hi2 = t >> 5;          // k-group / row-group selector
    const int strip = blockIdx.x * 2 + wv;
    const int n   = strip * 32 + col;
    const bool nv = (n < NW);

    __shared__ __align__(16) unsigned char Xs[2 * WV_STRIDE];  // 24 KB
    unsigned char* Xw = Xs + wv * WV_STRIDE;

    const int swz   = (col & 7) << 4;
    const int rbase = col * 128;
    // B-frag read addrs (WORK-relative): k = kc*16 + hi2*8 + j -> byte kc*32+hi2*16
    int rd[4];
    #pragma unroll
    for (int kc = 0; kc < 4; ++kc)
        rd[kc] = rbase + ((kc * 32 + hi2 * 16) ^ swz);

    // ---- stage inputs into WORK rows (lanes hi2==0; row = col) ----
    if (hi2 == 0) {
        const int w = min(strip * 32 + col, NW - 1);
        const float* xr = x + ((size_t)b * TT + w) * DD;
        f32x4 x0 = *(const f32x4*)(xr + 0);
        f32x4 x1 = *(const f32x4*)(xr + 4);
        f32x4 x2 = *(const f32x4*)(xr + 8);
        f32x4 x3 = *(const f32x4*)(xr + 12);
        float xl = xr[2 * DD + d];
        uint4 q0, q1, qz, zz;
        q0.x = pku(x0[0], x0[1]); q0.y = pku(x0[2], x0[3]);
        q0.z = pku(x1[0], x1[1]); q0.w = pku(x1[2], x1[3]);
        q1.x = pku(x2[0], x2[1]); q1.y = pku(x2[2], x2[3]);
        q1.z = pku(x3[0], x3[1]); q1.w = pku(x3[2], x3[3]);
        qz.x = pku(xl, 0.f); qz.y = 0u; qz.z = 0u; qz.w = 0u;
        zz.x = 0u; zz.y = 0u; zz.z = 0u; zz.w = 0u;
        *(uint4*)&Xw[rbase + (0  ^ swz)] = q0;   // k 0..7
        *(uint4*)&Xw[rbase + (16 ^ swz)] = q1;   // k 8..15
        *(uint4*)&Xw[rbase + (32 ^ swz)] = qz;   // k 16..23 (xl + 0)
        *(uint4*)&Xw[rbase + (48 ^ swz)] = zz;   // k 24..31 (pad)
    }
    // no fence: same-wave DS ordering; compiler inserts lgkmcnt waits

    const float A0f = a0[d], A1f = a1[d], A2f = a2[d];
    const h2t apk0 = __builtin_bit_cast(h2t, pku(A0f, A0f));
    const h2t apk1 = __builtin_bit_cast(h2t, pku(A1f, A1f));
    const h2t apk2 = __builtin_bit_cast(h2t, pku(A2f, A2f));

    // C tiles: col = col, row h = 32*mt + (reg&3) + 8*(reg>>2) + 4*hi2
    f32x16 C[2];

    auto zeroC = [&]() {
        #pragma unroll
        for (int mt = 0; mt < 2; ++mt)
            #pragma unroll
            for (int r = 0; r < 16; ++r) C[mt][r] = 0.0f;
    };
    auto biasInit = [&](const float* bp) {
        #pragma unroll
        for (int mt = 0; mt < 2; ++mt)
            #pragma unroll
            for (int g = 0; g < 4; ++g) {
                f32x4 bb = *(const f32x4*)(bp + 32 * mt + 8 * g + 4 * hi2);
                C[mt][4 * g + 0] = bb[0]; C[mt][4 * g + 1] = bb[1];
                C[mt][4 * g + 2] = bb[2]; C[mt][4 * g + 3] = bb[3];
            }
    };
    // K=64 GEMM, B from region `regoff` of WORK-space rows
    auto gemmK64 = [&](const _Float16* apk, int regoff) {
        #pragma unroll
        for (int kc = 0; kc < 4; ++kc) {
            half8 Bv = *(const half8*)&Xw[rd[kc] + regoff];
            #pragma unroll
            for (int mt = 0; mt < 2; ++mt) {
                half8 a = *(const half8*)(apk + (size_t)((mt * 4 + kc) * 64 + t) * 8);
                C[mt] = __builtin_amdgcn_mfma_f32_32x32x16_f16(a, Bv, C[mt], 0, 0, 0);
            }
        }
    };
    // write byte offset for (mt,g): h = 32mt+8g+4hi2 -> byte 64mt+16g+8hi2
    auto wroff = [&](int mt, int g) {
        return rbase + (((64 * mt + 16 * g) ^ swz) + 8 * hi2);
    };
    // forward: pack -> packed PReLU -> store to region
    auto preluStore = [&](h2t ap, int regoff) {
        #pragma unroll
        for (int mt = 0; mt < 2; ++mt)
            #pragma unroll
            for (int g = 0; g < 4; ++g) {
                unsigned lo_ = pku(C[mt][4 * g + 0], C[mt][4 * g + 1]);
                unsigned hi_ = pku(C[mt][4 * g + 2], C[mt][4 * g + 3]);
                h2t hl = __builtin_bit_cast(h2t, lo_);
                h2t hh = __builtin_bit_cast(h2t, hi_);
                hl = pmax(hl, hl * ap);
                hh = pmax(hh, hh * ap);
                uint2 p;
                p.x = __builtin_bit_cast(unsigned int, hl);
                p.y = __builtin_bit_cast(unsigned int, hh);
                *(uint2*)&Xw[wroff(mt, g) + regoff] = p;
            }
    };
    // backward: v' = v * d, d from sign of h' read from `hregoff`; store WORK
    auto dApplyStore = [&](h2t ap, int hregoff) {
        #pragma unroll
        for (int mt = 0; mt < 2; ++mt)
            #pragma unroll
            for (int g = 0; g < 4; ++g) {
                const int off = wroff(mt, g);
                uint2 hr = *(const uint2*)&Xw[off + hregoff];
                unsigned vx = pku(C[mt][4 * g + 0], C[mt][4 * g + 1]);
                unsigned vy = pku(C[mt][4 * g + 2], C[mt][4 * g + 3]);
                unsigned avx = __builtin_bit_cast(unsigned int,
                                   __builtin_bit_cast(h2t, vx) * ap);
                unsigned avy = __builtin_bit_cast(unsigned int,
                                   __builtin_bit_cast(h2t, vy) * ap);
                unsigned mx = ((hr.x & 0x80008000u) >> 15) * 0xFFFFu;
                unsigned my = ((hr.y & 0x80008000u) >> 15) * 0xFFFFu;
                uint2 p;
                p.x = (mx & avx) | (~mx & vx);
                p.y = (my & avy) | (~my & vy);
                *(uint2*)&Xw[off] = p;
            }
    };

    // ================= forward =================
    // L0: K=32 (kc 0..1)
    {
        const _Float16* apk = wsp + OA0F + (size_t)d * SZ_A0F;
        biasInit(b0 + d * HH);
        #pragma unroll
        for (int kc = 0; kc < 2; ++kc) {
            half8 Bv = *(const half8*)&Xw[rd[kc]];
            #pragma unroll
            for (int mt = 0; mt < 2; ++mt) {
                half8 a = *(const half8*)(apk + (size_t)((mt * 2 + kc) * 64 + t) * 8);
                C[mt] = __builtin_amdgcn_mfma_f32_32x32x16_f16(a, Bv, C[mt], 0, 0, 0);
            }
        }
    }
    preluStore(apk0, REG_H0);

    biasInit(b1 + d * HH);
    gemmK64(wsp + OA1F + (size_t)d * SZ_AH, REG_H0);
    preluStore(apk1, REG_H1);

    biasInit(b2 + d * HH);
    gemmK64(wsp + OA2F + (size_t)d * SZ_AH, REG_H1);

    // ---- h2 packed + residual dot + v2 init (no LDS round trip for d2) ----
    {
        uint2 h2p[2][4], w3p[2][4];
        float s = 0.0f;
        #pragma unroll
        for (int mt = 0; mt < 2; ++mt)
            #pragma unroll
            for (int g = 0; g < 4; ++g) {
                f32x4 w = *(const f32x4*)(W3 + d * HH + 32 * mt + 8 * g + 4 * hi2);
                w3p[mt][g].x = pku(w[0], w[1]);
                w3p[mt][g].y = pku(w[2], w[3]);
                unsigned lo_ = pku(C[mt][4 * g + 0], C[mt][4 * g + 1]);
                unsigned hi_ = pku(C[mt][4 * g + 2], C[mt][4 * g + 3]);
                h2t hl = __builtin_bit_cast(h2t, lo_);
                h2t hh = __builtin_bit_cast(h2t, hi_);
                hl = pmax(hl, hl * apk2);
                hh = pmax(hh, hh * apk2);
                h2p[mt][g].x = __builtin_bit_cast(unsigned int, hl);
                h2p[mt][g].y = __builtin_bit_cast(unsigned int, hh);
                s = fdot2(hl, __builtin_bit_cast(h2t, w3p[mt][g].x), s);
                s = fdot2(hh, __builtin_bit_cast(h2t, w3p[mt][g].y), s);
            }
        s += __shfl_xor(s, 32);   // combine the two h-halves (hi2 0/1)
        if (hi2 == 0 && nv)
            out[RES_OFF + ((size_t)b * NW + n) * DD + d] = s + b3[d];

        // v2 = w3 * d2 (d2 from h2 sign) -> WORK
        #pragma unroll
        for (int mt = 0; mt < 2; ++mt)
            #pragma unroll
            for (int g = 0; g < 4; ++g) {
                unsigned wax = __builtin_bit_cast(unsigned int,
                                   __builtin_bit_cast(h2t, w3p[mt][g].x) * apk2);
                unsigned way = __builtin_bit_cast(unsigned int,
                                   __builtin_bit_cast(h2t, w3p[mt][g].y) * apk2);
                unsigned mx = ((h2p[mt][g].x & 0x80008000u) >> 15) * 0xFFFFu;
                unsigned my = ((h2p[mt][g].y & 0x80008000u) >> 15) * 0xFFFFu;
                uint2 p;
                p.x = (mx & wax) | (~mx & w3p[mt][g].x);
                p.y = (my & way) | (~my & w3p[mt][g].y);
                *(uint2*)&Xw[wroff(mt, g)] = p;
            }
    }

    // ================= backward =================
    zeroC();
    gemmK64(wsp + OA2T + (size_t)d * SZ_AH, 0);
    dApplyStore(apk1, REG_H1);

    zeroC();
    gemmK64(wsp + OA1T + (size_t)d * SZ_AH, 0);
    dApplyStore(apk0, REG_H0);

    // G = W0T @ v0 : single M=32 tile; f = (reg&3) + 8*(reg>>2) + 4*hi2
    f32x16 G;
    {
        #pragma unroll
        for (int r = 0; r < 16; ++r) G[r] = 0.0f;
        const _Float16* apk = wsp + OA0T + (size_t)d * SZ_A0T;
        #pragma unroll
        for (int kc = 0; kc < 4; ++kc) {
            half8 Bv = *(const half8*)&Xw[rd[kc]];
            half8 a = *(const half8*)(apk + (size_t)(kc * 64 + t) * 8);
            G = __builtin_amdgcn_mfma_f32_32x32x16_f16(a, Bv, G, 0, 0, 0);
        }
    }

    // hist_jac: groups g=0,1 cover f 0..15 (f_base = 8g + 4*hi2)
    if (nv) {
        #pragma unroll
        for (int g = 0; g < 2; ++g) {
            f32x4 v;
            v[0] = G[4 * g + 0]; v[1] = G[4 * g + 1];
            v[2] = G[4 * g + 2]; v[3] = G[4 * g + 3];
            *(f32x4*)(out + HJ_OFF + ((size_t)d * NTOT + (size_t)b * NW + n) * 16
                      + 8 * g + 4 * hi2) = v;
        }
    }

    // log|g[16]|: f=16 -> reg 8, hi2==0 lanes
    {
        float ld = (hi2 == 0 && nv) ? __logf(fabsf(G[8])) : 0.0f;
        #pragma unroll
        for (int off = 32; off > 0; off >>= 1) ld += __shfl_down(ld, off);
        if (t == 0) partials[(b * DD + d) * NSTR + strip] = ld;
    }
}

__global__ void reduce_log(const float* __restrict__ partials, float* __restrict__ out)
{
    const int b = blockIdx.x;     // BB blocks x 64 threads
    const int t = threadIdx.x;
    float s = 0.0f;
    #pragma unroll
    for (int i = 0; i < 4; ++i) s += partials[b * (DD * NSTR) + t * 4 + i];
    #pragma unroll
    for (int off = 32; off > 0; off >>= 1) s += __shfl_down(s, off);
    if (t == 0) out[LOG_OFF + b] = s;
}

extern "C" void kernel_launch(void* const* d_in, const int* in_sizes, int n_in,
                              void* d_out, int out_size, void* d_ws, size_t ws_size,
                              hipStream_t stream)
{
    const float* x  = (const float*)d_in[0];
    const float* W0 = (const float*)d_in[1];
    const float* b0 = (const float*)d_in[2];
    const float* a0 = (const float*)d_in[3];
    const float* W1 = (const float*)d_in[4];
    const float* b1 = (const float*)d_in[5];
    const float* a1 = (const float*)d_in[6];
    const float* W2 = (const float*)d_in[7];
    const float* b2 = (const float*)d_in[8];
    const float* a2 = (const float*)d_in[9];
    const float* W3 = (const float*)d_in[10];
    const float* b3 = (const float*)d_in[11];

    float*     out      = (float*)d_out;
    _Float16*  wsp      = (_Float16*)d_ws;
    float*     partials = (float*)((char*)d_ws + (size_t)WTOT * 2);  // 16384 floats

    setup_weights<<<160, 1024, 0, stream>>>(W0, W1, W2, wsp);

    dim3 grid(GXB, BB, DD);   // 16 x 64 x 8 = 8192 blocks x 2 waves (32 win/wave)
    fused_mlp<<<grid, 128, 0, stream>>>(x, b0, a0, b1, a1, b2, a2, W3, b3,
                                        wsp, out, partials);
    reduce_log<<<BB, 64, 0, stream>>>(partials, out);
}